// Round 14
// baseline (1104.789 us; speedup 1.0000x reference)
//
#include <hip/hip_runtime.h>
#include <hip/hip_bf16.h>

// Transformer-XL forward, MI355X gfx950.
// Round 16: flash v5 -- in-loop block barriers replaced by free wave fences.
// Round-13 counters: flash 67us with NOTHING busy (Mfma 3.9%, VALU 18%,
// HBM 5%, all 1024 blocks resident) -> latency-bound, 4-wave lockstep from
// 2 __syncthreads()/iter. Both LDS handoffs are wave-PRIVATE (sD[w], sP[w]);
// same-wave DS ops execute in program order in HW, so only compiler
// reordering (v3's bug) must be fenced: __builtin_amdgcn_wave_barrier()
// (zero instructions). Waves now drift and overlap phases. Post-loop merge
// barriers (true cross-wave) stay. Everything else unchanged from round 15.

#define BQ 2
#define QL 512
#define ML 512
#define CL 1024    // QLEN + MLEN
#define RL 1536    // CLEN + QLEN
#define HD 1024
#define NH 16
#define DH 64
#define FF 4096
#define NLAYER 4

typedef const float* FP;
typedef const __hip_bfloat16* BP;
typedef unsigned short u16;
typedef unsigned long long u64;
typedef __attribute__((ext_vector_type(8))) __bf16 bf16x8;
typedef __attribute__((ext_vector_type(8))) unsigned short u16x8;
typedef __attribute__((ext_vector_type(4))) float f32x4;

static __device__ __forceinline__ float b2f(__hip_bfloat16 x) { return __bfloat162float(x); }
static __device__ __forceinline__ u16 f2u(float f) {
    union { __hip_bfloat16 h; u16 u; } c; c.h = __float2bfloat16(f); return c.u;
}
static __device__ __forceinline__ float u2f(u16 u) {
    union { float f; unsigned int i; } c; c.i = ((unsigned int)u) << 16; return c.f;
}

// wave-local LDS write->read fence: DS ops from one wave are in-order in HW;
// this only pins the compiler's program order (emits no instructions).
static __device__ __forceinline__ void wave_lds_fence() {
    __builtin_amdgcn_wave_barrier();
}

// async 16B global->LDS (gfx950). Per-lane global addr; LDS dest must equal
// wave-uniform base + lane*16B in the exact lane order.
static __device__ __forceinline__ void gll16(const u16* g, u16* l) {
    __builtin_amdgcn_global_load_lds(
        (__attribute__((address_space(1))) void*)(u16*)g,
        (__attribute__((address_space(3))) void*)l, 16, 0, 0);
}

// flags[0] = 1 if float inputs are fp32, 0 if bf16
// flags[1] = 1 if segment_matrix is int32, 0 if int8
__global__ void sniff_kernel(const unsigned int* __restrict__ ln1_gamma,
                             const unsigned char* __restrict__ seg,
                             int* __restrict__ flags) {
    if (threadIdx.x == 0) {
        flags[0] = (ln1_gamma[0] == 0x3F800000u) ? 1 : 0;
        int int32ok = 1;
        for (int i = 0; i < 256; ++i)
            if ((i & 3) != 0 && seg[i] != 0) { int32ok = 0; break; }
        flags[1] = int32ok;
    }
}

__global__ void canon_kernel(FP inf, BP inb, u16* __restrict__ out,
                             int n, const int* __restrict__ flags) {
    int i = blockIdx.x * 256 + threadIdx.x;
    if (i >= n) return;
    out[i] = flags[0] ? f2u(inf[i]) : ((const u16*)inb)[i];
}

__global__ void out_write_kernel(const u16* __restrict__ in, void* __restrict__ out,
                                 int n, const int* __restrict__ flags) {
    int i = blockIdx.x * 256 + threadIdx.x;
    if (i >= n) return;
    if (flags[0]) ((float*)out)[i] = u2f(in[i]);
    else          ((u16*)out)[i] = in[i];
}

// maskT[b][j][i] = bf16(mask[b][i][j] * -1e30) with LSB = segment bit.
__global__ __launch_bounds__(256) void segmask_packT_kernel(
    const void* __restrict__ seg, FP maskf, BP maskb,
    u16* __restrict__ maskT, const int* __restrict__ flags) {
    __shared__ u16 t[32][33];
    const int tid = threadIdx.x;
    const int j0 = blockIdx.x * 32, i0 = blockIdx.y * 32, b = blockIdx.z;
    const int tc = tid & 31, tr = tid >> 5;
    const int f32 = flags[0], s32 = flags[1];
    #pragma unroll
    for (int p = 0; p < 4; ++p) {
        int i = i0 + p * 8 + tr;
        size_t gi = ((size_t)(b * QL + i)) * CL + j0 + tc;
        int sv = s32 ? ((const int*)seg)[gi] : (int)((const signed char*)seg)[gi];
        float mk = f32 ? maskf[gi] : b2f(maskb[gi]);
        t[p * 8 + tr][tc] = (u16)((f2u(mk * -1e30f) & 0xFFFEu) | (sv ? 1u : 0u));
    }
    __syncthreads();
    #pragma unroll
    for (int p = 0; p < 4; ++p) {
        int j = j0 + p * 8 + tr;
        maskT[((size_t)(b * CL + j)) * QL + i0 + tc] = t[tc][p * 8 + tr];
    }
}

// in: R x Cc (dual float), out: Cc x R bf16 (k-contiguous B^T)
__global__ __launch_bounds__(256) void transpose_kernel(
    FP inf, BP inb, u16* __restrict__ out, int R, int Cc,
    const int* __restrict__ flags) {
    __shared__ float t[32][33];
    const int tid = threadIdx.x;
    const int c0 = blockIdx.x * 32, r0 = blockIdx.y * 32;
    const int tc = tid & 31, tr = tid >> 5;
    const int f32 = flags[0];
    #pragma unroll
    for (int p = 0; p < 4; ++p) {
        int r = r0 + p * 8 + tr;
        size_t gi = (size_t)r * Cc + c0 + tc;
        t[p * 8 + tr][tc] = f32 ? inf[gi] : b2f(inb[gi]);
    }
    __syncthreads();
    #pragma unroll
    for (int p = 0; p < 4; ++p) {
        int c = c0 + p * 8 + tr;
        out[(size_t)c * R + r0 + tc] = f2u(t[tc][p * 8 + tr]);
    }
}

// batched 1024x1024 transpose of w_q/w_k/w_v/w_r -> W4 segments (z picks).
__global__ __launch_bounds__(256) void transpose4_kernel(
    FP aqf, BP aqb, FP akf, BP akb, FP avf, BP avb, FP arf, BP arb,
    u16* __restrict__ W4, const int* __restrict__ flags) {
    __shared__ float t[32][33];
    const int tid = threadIdx.x;
    const int c0 = blockIdx.x * 32, r0 = blockIdx.y * 32, z = blockIdx.z;
    const int tc = tid & 31, tr = tid >> 5;
    const int f32 = flags[0];
    FP inf; BP inb;
    if (z == 0)      { inf = aqf; inb = aqb; }
    else if (z == 1) { inf = akf; inb = akb; }
    else if (z == 2) { inf = avf; inb = avb; }
    else             { inf = arf; inb = arb; }
    u16* out = W4 + (size_t)z * (HD * HD);
    #pragma unroll
    for (int p = 0; p < 4; ++p) {
        int r = r0 + p * 8 + tr;
        size_t gi = (size_t)r * HD + c0 + tc;
        t[p * 8 + tr][tc] = f32 ? inf[gi] : b2f(inb[gi]);
    }
    __syncthreads();
    #pragma unroll
    for (int p = 0; p < 4; ++p) {
        int c = c0 + p * 8 + tr;
        out[(size_t)c * HD + r0 + tc] = f2u(t[tc][p * 8 + tr]);
    }
}

// ---------------- 128x128 GEMM core, BK=32, async LDS staging ----------------
__device__ __forceinline__ void gemm128_core(
    const u16* __restrict__ A, int lda, const u16* __restrict__ Bt, int ldb,
    int K, int tid, u16* sA, u16* sB, f32x4 (&acc)[4][4])
{
    const int lane = tid & 63, w = tid >> 6;
    const int wm = (w & 1) * 64, wn = (w >> 1) * 64;
    const int lr = lane & 15, quad = lane >> 4;
    const int srow = lane >> 2;           // 16 rows per instr, 4 lanes/row
    const int sch = (lane & 3) * 8;       // 8 u16 = 16B per lane

    for (int k0 = 0; k0 < K; k0 += 32) {
        #pragma unroll
        for (int j = 0; j < 2; ++j) {     // wave w stages rows w*32+j*16 .. +15
            int rb = w * 32 + j * 16;
            gll16(&A[(size_t)(rb + srow) * lda + k0 + sch], &sA[rb * 32 + lane * 8]);
            gll16(&Bt[(size_t)(rb + srow) * ldb + k0 + sch], &sB[rb * 32 + lane * 8]);
        }
        __syncthreads();                  // drains vmcnt, then barrier
        bf16x8 af[4], bf[4];
        #pragma unroll
        for (int mi = 0; mi < 4; ++mi)
            af[mi] = *(const bf16x8*)&sA[(wm + mi * 16 + lr) * 32 + quad * 8];
        #pragma unroll
        for (int ni = 0; ni < 4; ++ni)
            bf[ni] = *(const bf16x8*)&sB[(wn + ni * 16 + lr) * 32 + quad * 8];
        #pragma unroll
        for (int mi = 0; mi < 4; ++mi)
            #pragma unroll
            for (int ni = 0; ni < 4; ++ni)
                acc[mi][ni] = __builtin_amdgcn_mfma_f32_16x16x32_bf16(
                    af[mi], bf[ni], acc[mi][ni], 0, 0, 0);
        __syncthreads();
    }
}

#define ACC_INIT(acc) \
    _Pragma("unroll") for (int mi = 0; mi < 4; ++mi) \
        _Pragma("unroll") for (int ni = 0; ni < 4; ++ni) \
            acc[mi][ni] = (f32x4){0.f, 0.f, 0.f, 0.f};

// ---------------- merged q/k/v/r projection GEMM (128-tile) ----------------
// K/V segments read context rows directly: ctx row = b*CL + r; r<ML from
// memsB[layer][b], else from X[b]. V segment writes VT[bn][d][j] directly.
__global__ __launch_bounds__(256) void proj4_gemm(
    const u16* __restrict__ X, const u16* __restrict__ memsL,
    const u16* __restrict__ PE, const u16* __restrict__ W4,
    u16* __restrict__ Qb, u16* __restrict__ Kb,
    u16* __restrict__ VT, u16* __restrict__ Rb)
{
    __shared__ __align__(16) u16 sA[128 * 32];
    __shared__ __align__(16) u16 sB[128 * 32];
    const int tid = threadIdx.x;
    const int by = blockIdx.y;
    const u16* Abase; u16* Cbase = nullptr; int seg, mb;
    if (by < 8)       { seg = 0; mb = by;      Abase = X + (size_t)mb * 128 * HD; Cbase = Qb; }
    else if (by < 24) { seg = 1; mb = by - 8;  Cbase = Kb; Abase = nullptr; }
    else if (by < 40) { seg = 2; mb = by - 24; Abase = nullptr; }
    else              { seg = 3; mb = by - 40; Abase = PE + (size_t)mb * 128 * HD; Cbase = Rb; }
    if (seg == 1 || seg == 2) {
        int b = mb >> 3, r0 = (mb & 7) * 128;
        Abase = (r0 < ML) ? memsL + ((size_t)(b * ML + r0)) * HD
                          : X + ((size_t)(b * QL + (r0 - ML))) * HD;
    }
    const int m0 = mb * 128, n0 = blockIdx.x * 128;

    f32x4 acc[4][4];
    ACC_INIT(acc)
    gemm128_core(Abase, HD, W4 + (size_t)seg * HD * HD + (size_t)n0 * HD, HD, HD,
                 tid, sA, sB, acc);

    const int lane = tid & 63, w = tid >> 6;
    const int wm = (w & 1) * 64, wn = (w >> 1) * 64;
    const int lr = lane & 15, quad = lane >> 4;
    if (seg != 2) {
        #pragma unroll
        for (int ni = 0; ni < 4; ++ni) {
            int col = n0 + wn + ni * 16 + lr;
            #pragma unroll
            for (int mi = 0; mi < 4; ++mi) {
                int row = m0 + wm + mi * 16 + quad * 4;
                #pragma unroll
                for (int r = 0; r < 4; ++r)
                    Cbase[(size_t)(row + r) * HD + col] = f2u(acc[mi][ni][r]);
            }
        }
    } else {
        // V: write VT[(b*NH+n)][d][j], j contiguous (4 rows -> ushort4)
        #pragma unroll
        for (int ni = 0; ni < 4; ++ni) {
            int col = n0 + wn + ni * 16 + lr;
            int nh = col >> 6, d = col & 63;
            #pragma unroll
            for (int mi = 0; mi < 4; ++mi) {
                int row = m0 + wm + mi * 16 + quad * 4;
                int b = row >> 10, j = row & 1023;
                ushort4 o;
                #pragma unroll
                for (int r = 0; r < 4; ++r) (&o.x)[r] = f2u(acc[mi][ni][r]);
                *(ushort4*)&VT[(((size_t)(b * NH + nh) * DH + d) * CL + j)] = o;
            }
        }
    }
}

// ---------------- split-K 128-tile GEMM: fp32 partials ----------------
__global__ __launch_bounds__(256) void gemm128_splitk(
    const u16* __restrict__ A, const u16* __restrict__ Bt,
    float* __restrict__ part, int N, int Kfull, int Kc, size_t zstride)
{
    __shared__ __align__(16) u16 sA[128 * 32];
    __shared__ __align__(16) u16 sB[128 * 32];
    const int tid = threadIdx.x;
    const int n0 = blockIdx.x * 128, m0 = blockIdx.y * 128, z = blockIdx.z;
    f32x4 acc[4][4];
    ACC_INIT(acc)
    gemm128_core(A + (size_t)m0 * Kfull + z * Kc, Kfull,
                 Bt + (size_t)n0 * Kfull + z * Kc, Kfull, Kc,
                 tid, sA, sB, acc);

    float* P = part + (size_t)z * zstride;
    const int lane = tid & 63, w = tid >> 6;
    const int wm = (w & 1) * 64, wn = (w >> 1) * 64;
    const int lr = lane & 15, quad = lane >> 4;
    #pragma unroll
    for (int ni = 0; ni < 4; ++ni) {
        int col = n0 + wn + ni * 16 + lr;
        #pragma unroll
        for (int mi = 0; mi < 4; ++mi) {
            int row = m0 + wm + mi * 16 + quad * 4;
            #pragma unroll
            for (int r = 0; r < 4; ++r)
                P[(size_t)(row + r) * N + col] = acc[mi][ni][r];
        }
    }
}

// ---------------- reduce(NPART partials) [+bias] + residual -> LayerNorm ----
template <bool HASBIAS, int NPART>
__global__ __launch_bounds__(256) void reduce_add_ln(
    const float* __restrict__ part, FP biasf, BP biasb,
    const u16* __restrict__ resid, FP gf, BP gb, FP bef, BP beb,
    u16* __restrict__ O, const int* __restrict__ flags)
{
    const int row = blockIdx.x;               // B*QL rows of HD
    const int tid = threadIdx.x;
    const int wid = tid >> 6, lane = tid & 63;
    __shared__ float r1[4], r2[4];
    const int f32 = flags[0];
    float v[4];
    #pragma unroll
    for (int c = 0; c < 4; ++c) {
        int h = c * 256 + tid;
        size_t idx = (size_t)row * HD + h;
        float s = 0.f;
        #pragma unroll
        for (int k = 0; k < NPART; ++k)
            s += part[idx + (size_t)k * 1048576];
        if (HASBIAS) s += f32 ? biasf[h] : b2f(biasb[h]);
        v[c] = s + u2f(resid[idx]);
    }
    float s = v[0] + v[1] + v[2] + v[3];
    #pragma unroll
    for (int o = 32; o > 0; o >>= 1) s += __shfl_xor(s, o);
    if (lane == 0) r1[wid] = s;
    __syncthreads();
    float mu = (r1[0] + r1[1] + r1[2] + r1[3]) * (1.0f / HD);
    float q = 0.f;
    #pragma unroll
    for (int c = 0; c < 4; ++c) { float d = v[c] - mu; q += d * d; }
    #pragma unroll
    for (int o = 32; o > 0; o >>= 1) q += __shfl_xor(q, o);
    if (lane == 0) r2[wid] = q;
    __syncthreads();
    float var = (r2[0] + r2[1] + r2[2] + r2[3]) * (1.0f / HD);
    float inv = rsqrtf(var + 1e-12f);
    #pragma unroll
    for (int c = 0; c < 4; ++c) {
        int h = c * 256 + tid;
        float g = f32 ? gf[h] : b2f(gb[h]);
        float be = f32 ? bef[h] : b2f(beb[h]);
        O[(size_t)row * HD + h] = f2u((v[c] - mu) * inv * g + be);
    }
}

// ---------------- reduce(2 partials) + bias + relu -> bf16 (FFN1) ----------
__global__ __launch_bounds__(256) void reduce_bias_relu_kernel(
    const float* __restrict__ part, FP b1f, BP b1b,
    u16* __restrict__ Out, const int* __restrict__ flags)
{
    const int g = blockIdx.x * 256 + threadIdx.x;       // float4 index
    const float4 p0 = ((const float4*)part)[g];
    const float4 p1 = ((const float4*)(part + 4194304))[g];
    const int col = (g * 4) & (FF - 1);
    const int f32 = flags[0];
    ushort4 o;
    #pragma unroll
    for (int j = 0; j < 4; ++j) {
        float bv = f32 ? b1f[col + j] : b2f(b1b[col + j]);
        float v = (&p0.x)[j] + (&p1.x)[j] + bv;
        (&o.x)[j] = f2u(fmaxf(v, 0.0f));
    }
    ((ushort4*)Out)[g] = o;
}

// ---------------- ef2: (q + segment_bias) . segment_encoding[l] ----------------
__global__ void ef2_kernel(const u16* __restrict__ Qb, FP sbf, BP sbb,
                           FP sef, BP seb, float* __restrict__ EF,
                           const int* __restrict__ flags) {
    int t = blockIdx.x * 256 + threadIdx.x;
    if (t >= BQ * NH * QL) return;
    int i = t % QL;
    int n = (t / QL) % NH;
    int b = t / (QL * NH);
    float e0 = 0.f, e1 = 0.f;
    const int f32 = flags[0];
    const u16* qrow = &Qb[((size_t)(b * QL + i) * NH + n) * DH];
    for (int d0 = 0; d0 < DH; d0 += 8) {
        u16x8 qv = *(const u16x8*)&qrow[d0];
        #pragma unroll
        for (int j = 0; j < 8; ++j) {
            int d = d0 + j;
            float sbv = f32 ? sbf[n * DH + d] : b2f(sbb[n * DH + d]);
            float s0 = f32 ? sef[(0 * NH + n) * DH + d] : b2f(seb[(0 * NH + n) * DH + d]);
            float s1 = f32 ? sef[(1 * NH + n) * DH + d] : b2f(seb[(1 * NH + n) * DH + d]);
            float qv_f = u2f(qv[j]) + sbv;
            e0 += qv_f * s0;
            e1 += qv_f * s1;
        }
    }
    EF[(size_t)t * 2 + 0] = e0;
    EF[(size_t)t * 2 + 1] = e1;
}

// ---------------- CK[bn][j] = cb_n . k_j ; PR[bn][rr] = pb_n . r_rr ----------------
__global__ void ckpr_kernel(const u16* __restrict__ Kb, const u16* __restrict__ Rb,
                            FP cbf, BP cbb, FP pbf, BP pbb,
                            float* __restrict__ CK, float* __restrict__ PR,
                            const int* __restrict__ flags) {
    int t = blockIdx.x * 256 + threadIdx.x;
    const int f32 = flags[0];
    if (t < 32 * CL) {
        int bn = t >> 10, j = t & (CL - 1);
        int b = bn >> 4, n = bn & 15;
        float s = 0.f;
        const u16* krow = &Kb[((size_t)(b * CL + j) * NH + n) * DH];
        for (int d0 = 0; d0 < DH; d0 += 8) {
            u16x8 kv = *(const u16x8*)&krow[d0];
            #pragma unroll
            for (int jj = 0; jj < 8; ++jj) {
                int d = d0 + jj;
                float c = f32 ? cbf[n * DH + d] : b2f(cbb[n * DH + d]);
                s += c * u2f(kv[jj]);
            }
        }
        CK[t] = s;
    } else {
        int t2 = t - 32 * CL;
        if (t2 >= 32 * RL) return;
        int bn = t2 / RL, rr = t2 % RL;
        int b = bn >> 4, n = bn & 15;
        float s = 0.f;
        const u16* rrow = &Rb[((size_t)(b * RL + rr) * NH + n) * DH];
        for (int d0 = 0; d0 < DH; d0 += 8) {
            u16x8 rv = *(const u16x8*)&rrow[d0];
            #pragma unroll
            for (int jj = 0; jj < 8; ++jj) {
                int d = d0 + jj;
                float c = f32 ? pbf[n * DH + d] : b2f(pbb[n * DH + d]);
                s += c * u2f(rv[jj]);
            }
        }
        PR[(size_t)bn * RL + rr] = s;
    }
}

// ---------------- fused flash attention v5 ----------------
// v4 + in-loop block barriers -> free wave fences (handoffs are wave-private;
// same-wave DS ops are in-order in HW; fence only pins compiler order).
#define FA_SP 72
#define FA_SD 84
__global__ __launch_bounds__(256, 4) void flash_attn_kernel(
    const u16* __restrict__ Qb, const u16* __restrict__ Kb,
    const u16* __restrict__ Rb, const u16* __restrict__ VT,
    const float* __restrict__ CK, const float* __restrict__ PR,
    const float* __restrict__ EF,
    const u16* __restrict__ maskT, u16* __restrict__ AT)
{
    __shared__ __align__(16) u16 sP[4][16 * FA_SP];
    __shared__ __align__(16) float sD[4][16 * FA_SD];   // cmb aliases after loop

    const int tid = threadIdx.x;
    const int w = tid >> 6;
    const int lane = tid & 63;
    const int lr = lane & 15, quad = lane >> 4;

    const int blin = blockIdx.x;
    const int xcd = blin & 7, slot = blin >> 3;
    const int bn = xcd + 8 * (slot >> 5);      // head; all 32 i-tiles same XCD
    const int itile = slot & 31;
    const int b = bn >> 4, n = bn & 15;
    const int i0 = itile * 16;

    u16* myP = sP[w];
    float* myD = sD[w];

    const size_t qoff = ((size_t)(b * QL + i0 + lr) * NH + n) * DH + quad * 8;
    const bf16x8 q0 = *(const bf16x8*)&Qb[qoff];
    const bf16x8 q1 = *(const bf16x8*)&Qb[qoff + 32];

    float ef0[4], ef1[4];
    #pragma unroll
    for (int r = 0; r < 4; ++r) {
        size_t e = ((size_t)bn * QL + i0 + quad * 4 + r) * 2;
        ef0[r] = EF[e]; ef1[r] = EF[e + 1];
    }

    f32x4 accO[4];
    #pragma unroll
    for (int c = 0; c < 4; ++c) accO[c] = (f32x4){0.f, 0.f, 0.f, 0.f};
    float m[4], l[4];
    #pragma unroll
    for (int r = 0; r < 4; ++r) { m[r] = -1e38f; l[r] = 0.f; }

    #pragma unroll 1
    for (int t = 0; t < 4; ++t) {
        const int j0 = w * 64 + t * 256;
        const int base16 = 497 - i0 + j0;     // rr at p=0; p = 15-ilw+jl

        // ---- QK: preload 8 K-frags (short live range), 8 MFMA ----
        bf16x8 kf[8];
        const u16* kbase = &Kb[((size_t)(b * CL + j0 + lr) * NH + n) * DH + quad * 8];
        #pragma unroll
        for (int ct = 0; ct < 4; ++ct) {
            const u16* kp = kbase + (size_t)ct * 16 * (NH * DH);
            kf[ct * 2]     = *(const bf16x8*)kp;
            kf[ct * 2 + 1] = *(const bf16x8*)(kp + 32);
        }
        f32x4 acc[4];
        #pragma unroll
        for (int c = 0; c < 4; ++c) acc[c] = (f32x4){0.f, 0.f, 0.f, 0.f};
        #pragma unroll
        for (int ct = 0; ct < 4; ++ct) {
            acc[ct] = __builtin_amdgcn_mfma_f32_16x16x32_bf16(q0, kf[ct * 2], acc[ct], 0, 0, 0);
            acc[ct] = __builtin_amdgcn_mfma_f32_16x16x32_bf16(q1, kf[ct * 2 + 1], acc[ct], 0, 0, 0);
        }

        // ---- bd per fragment: rf pair + PR -> 2 MFMA -> LDS (one frag live) ----
        #pragma unroll
        for (int f = 0; f < 5; ++f) {
            int rr = base16 + f * 16 + lr;
            rr = rr > RL - 1 ? RL - 1 : rr;   // p>=79 lanes: computed, never read
            const u16* rp = &Rb[((size_t)(b * RL + rr) * NH + n) * DH + quad * 8];
            bf16x8 rf0 = *(const bf16x8*)rp;
            bf16x8 rf1 = *(const bf16x8*)(rp + 32);
            float prv = PR[(size_t)bn * RL + rr];
            f32x4 bd = (f32x4){0.f, 0.f, 0.f, 0.f};
            bd = __builtin_amdgcn_mfma_f32_16x16x32_bf16(q0, rf0, bd, 0, 0, 0);
            bd = __builtin_amdgcn_mfma_f32_16x16x32_bf16(q1, rf1, bd, 0, 0, 0);
            #pragma unroll
            for (int r = 0; r < 4; ++r)
                myD[(quad * 4 + r) * FA_SD + f * 16 + lr] = bd[r] + prv;
        }
        wave_lds_fence();   // wave-local handoff: bd writes -> score reads

        // ---- V preload (covers scores+softmax latency; consumed by PV) ----
        bf16x8 vf[8];
        #pragma unroll
        for (int ct = 0; ct < 4; ++ct) {
            const u16* vp = &VT[((size_t)bn * DH + ct * 16 + lr) * CL + j0 + quad * 8];
            vf[ct * 2]     = *(const bf16x8*)vp;
            vf[ct * 2 + 1] = *(const bf16x8*)(vp + 32);
        }

        // ---- scores ----
        #pragma unroll
        for (int ct = 0; ct < 4; ++ct) {
            float ckv = CK[(size_t)bn * CL + j0 + ct * 16 + lr];
            u64 mq = *(const u64*)&maskT[((size_t)(b * CL + j0 + ct * 16 + lr)) * QL + i0 + quad * 4];
            #pragma unroll
            for (int r = 0; r < 4; ++r) {
                int ilw = quad * 4 + r;
                int p = 15 - ilw + ct * 16 + lr;
                float bdv = myD[ilw * FA_SD + p];
                u16 mv = (u16)(mq >> (16 * r));
                float efv = (mv & 1) ? ef1[r] : ef0[r];
                float mka = u2f((u16)(mv & 0xFFFEu));
                acc[ct][r] = (acc[ct][r] + bdv + ckv + efv) * 0.125f + mka;
            }
        }

        // ---- online softmax ----
        float a[4];
        #pragma unroll
        for (int r = 0; r < 4; ++r) {
            float tm = fmaxf(fmaxf(acc[0][r], acc[1][r]), fmaxf(acc[2][r], acc[3][r]));
            tm = fmaxf(tm, __shfl_xor(tm, 1));
            tm = fmaxf(tm, __shfl_xor(tm, 2));
            tm = fmaxf(tm, __shfl_xor(tm, 4));
            tm = fmaxf(tm, __shfl_xor(tm, 8));
            float mn = fmaxf(m[r], tm);
            a[r] = __expf(m[r] - mn);
            m[r] = mn;
        }
        float ts[4] = {0.f, 0.f, 0.f, 0.f};
        #pragma unroll
        for (int ct = 0; ct < 4; ++ct)
            #pragma unroll
            for (int r = 0; r < 4; ++r) {
                float pv = __expf(acc[ct][r] - m[r]);
                ts[r] += pv;
                myP[(quad * 4 + r) * FA_SP + ct * 16 + lr] = f2u(pv);
            }
        #pragma unroll
        for (int r = 0; r < 4; ++r) {
            float s = ts[r];
            s += __shfl_xor(s, 1);
            s += __shfl_xor(s, 2);
            s += __shfl_xor(s, 4);
            s += __shfl_xor(s, 8);
            l[r] = l[r] * a[r] + s;
            #pragma unroll
            for (int c = 0; c < 4; ++c) accO[c][r] *= a[r];
        }
        wave_lds_fence();   // wave-local handoff: P writes -> PV reads

        // ---- PV ----
        const bf16x8 pa0 = *(const bf16x8*)&myP[lr * FA_SP + quad * 8];
        const bf16x8 pa1 = *(const bf16x8*)&myP[lr * FA_SP + 32 + quad * 8];
        #pragma unroll
        for (int ct = 0; ct < 4; ++ct) {
            accO[ct] = __builtin_amdgcn_mfma_f32_16x16x32_bf16(pa0, vf[ct * 2], accO[ct], 0, 0, 0);
            accO[ct] = __builtin_amdgcn_mfma_f32_16x16x32_bf16(pa1, vf[ct * 2 + 1], accO[ct], 0, 0, 0);
        }
    }
    // ---- merge the 4 j-split partials (LDS aliased over sD), write AT ----
    __syncthreads();                         // cross-wave: all done with sD scratch
    float* cmb = &sD[0][0];
    if (w != 0) {
        float* c = &cmb[((w - 1) * 64 + lane) * 25];
        #pragma unroll
        for (int ct = 0; ct < 4; ++ct)
            #pragma unroll
            for (int r = 0; r < 4; ++r) c[ct * 4 + r] = accO[ct][r];
        #pragma unroll
        for (int r = 0; r < 4; ++r) { c[16 + r] = m[r]; c[20 + r] = l[r]; }
    }
    __syncthreads();
    if (w == 0) {
        float M[4], es[4], eo[3][4], lt[4];
        #pragma unroll
        for (int r = 0; r < 4; ++r) M[r] = m[r];
        #pragma unroll
        for (int k = 0; k < 3; ++k) {
            const float* c = &cmb[(k * 64 + lane) * 25];
            #pragma unroll
            for (int r = 0; r < 4; ++r) M[r] = fmaxf(M[r], c[16 + r]);
        }
        #pragma unroll
        for (int r = 0; r < 4; ++r) { es[r] = __expf(m[r] - M[r]); lt[r] = l[r] * es[r]; }
        #pragma unroll
        for (int k = 0; k < 3; ++k) {
            const float* c = &cmb[(k * 64 + lane) * 25];
            #pragma unroll
            for (int r = 0; r < 4; ++r) {
                eo[k][r] = __expf(c[16 + r] - M[r]);
                lt[r] += c[20 + r] * eo[k][r];
            }
        }
        #pragma unroll
        for (int ct = 0; ct < 4; ++ct)
            #pragma unroll
            for (int r = 0; r < 4; ++r) {
                float o = accO[ct][r] * es[r];
                #pragma unroll
                for (int k = 0; k < 3; ++k)
                    o += cmb[(k * 64 + lane) * 25 + ct * 4 + r] * eo[k][r];
                AT[((size_t)(b * QL + i0 + quad * 4 + r) * NH + n) * DH + ct * 16 + lr]
                    = f2u(o / lt[r]);
            }
    }
}

extern "C" void kernel_launch(void* const* d_in, const int* in_sizes, int n_in,
                              void* d_out, int out_size, void* d_ws, size_t ws_size,
                              hipStream_t stream) {
    (void)in_sizes; (void)n_in; (void)out_size; (void)ws_size;
    const void* content_stream = d_in[0];
    const void* content_mask   = d_in[1];
    const void* pos_enc        = d_in[2];
    const void* seg_mat        = d_in[3];
    const void* mems           = d_in[4];
    const void* w_q            = d_in[5];
    const void* w_k            = d_in[6];
    const void* w_v            = d_in[7];
    const void* w_r            = d_in[8];
    const void* w_o            = d_in[9];
    const void* ffn_w1         = d_in[10];
    const void* ffn_b1         = d_in[11];
    const void* ffn_w2         = d_in[12];
    const void* ffn_b2         = d_in[13];
    const void* ln1_g          = d_in[14];
    const void* ln1_b          = d_in[15];
    const void* ln2_g          = d_in[16];
    const void* ln2_b          = d_in[17];
    const void* cb             = d_in[18];
    const void* pb             = d_in[19];
    const void* sb             = d_in[20];
    const void* se             = d_in[21];

    float* SC    = (float*)d_ws;              // F1 0..8MB
    float* PART  = SC + 4194304;              // +16MB..+48MB (8x4MB / 2x16MB)
    float* EF    = SC + 16777216;             // +64MB
    float* CK    = EF + 32768;
    float* PR    = CK + 32768;
    int*   flags = (int*)(PR + 49152);
    u16*   bws   = (u16*)(flags + 16);

    u16* MEMSB = bws;                 // L*B*ML*HD bf16 (8MB)
    u16* X   = MEMSB + 4194304;       u16* Y   = X   + 1048576;
    u16* Qb  = Y   + 1048576;         u16* Kb  = Qb  + 1048576;
    u16* Rb  = Kb  + 2097152;         u16* PE  = Rb  + 3145728;
    u16* AT  = PE  + 3145728;
    u16* W4  = AT  + 1048576;         // WQT|WKT|WVT|WRT contiguous
    u16* WOc = W4  + 4194304;         u16* W1T = WOc + 1048576;
    u16* W2T = W1T + 4194304;
    u16* F1  = (u16*)SC;              // bytes 0..8MB
    u16* VT  = (u16*)(SC + 12582912); // +48MB..+52MB
    u16* maskT = (u16*)(SC + 13631488); // +52MB..+54MB

    const size_t wstride   = (size_t)HD * HD;

    const dim3 blk(256);
    #define DUAL(base, off) ((FP)(base) + (off)), ((BP)(base) + (off))

    sniff_kernel<<<dim3(1), dim3(64), 0, stream>>>(
        (const unsigned int*)ln1_g, (const unsigned char*)seg_mat, flags);

    canon_kernel<<<dim3((BQ * QL * HD) / 256), blk, 0, stream>>>(
        DUAL(content_stream, 0), X, BQ * QL * HD, flags);
    canon_kernel<<<dim3((BQ * RL * HD) / 256), blk, 0, stream>>>(
        DUAL(pos_enc, 0), PE, BQ * RL * HD, flags);
    canon_kernel<<<dim3((NLAYER * BQ * ML * HD) / 256), blk, 0, stream>>>(
        DUAL(mems, 0), MEMSB, NLAYER * BQ * ML * HD, flags);
    segmask_packT_kernel<<<dim3(CL / 32, QL / 32, BQ), blk, 0, stream>>>(
        seg_mat, DUAL(content_mask, 0), maskT, flags);

    for (int l = 0; l < NLAYER; ++l) {
        transpose4_kernel<<<dim3(32, 32, 4), blk, 0, stream>>>(
            DUAL(w_q, (size_t)l * wstride), DUAL(w_k, (size_t)l * wstride),
            DUAL(w_v, (size_t)l * wstride), DUAL(w_r, (size_t)l * wstride),
            W4, flags);
        canon_kernel<<<dim3((HD * HD) / 256), blk, 0, stream>>>(
            DUAL(w_o, (size_t)l * wstride), WOc, HD * HD, flags);
        transpose_kernel<<<dim3(FF / 32, HD / 32), blk, 0, stream>>>(
            DUAL(ffn_w1, (size_t)l * HD * FF), W1T, HD, FF, flags);
        transpose_kernel<<<dim3(HD / 32, FF / 32), blk, 0, stream>>>(
            DUAL(ffn_w2, (size_t)l * FF * HD), W2T, FF, HD, flags);

        proj4_gemm<<<dim3(8, 64), blk, 0, stream>>>(
            X, MEMSB + (size_t)l * BQ * ML * HD, PE, W4, Qb, Kb, VT, Rb);

        ef2_kernel<<<dim3((BQ * NH * QL) / 256), blk, 0, stream>>>(
            Qb, DUAL(sb, 0), DUAL(se, (size_t)l * 2 * NH * DH), EF, flags);
        ckpr_kernel<<<dim3((32 * CL + 32 * RL) / 256), blk, 0, stream>>>(
            Kb, Rb, DUAL(cb, 0), DUAL(pb, 0), CK, PR, flags);

        flash_attn_kernel<<<dim3(1024), blk, 0, stream>>>(
            Qb, Kb, Rb, VT, CK, PR, EF, maskT, AT);

        // o-proj: split-K z=8 (Kc=128) -> 512 blocks
        gemm128_splitk<<<dim3(8, 8, 8), blk, 0, stream>>>(
            AT, WOc, PART, HD, HD, 128, 1048576);
        reduce_add_ln<false, 8><<<dim3(BQ * QL), blk, 0, stream>>>(
            PART, (FP)nullptr, (BP)nullptr, X,
            DUAL(ln1_g, (size_t)l * HD), DUAL(ln1_b, (size_t)l * HD), Y, flags);

        // FFN1: split-K z=2 (Kc=512) -> 512 blocks; reduce+bias+relu pass
        gemm128_splitk<<<dim3(FF / 128, 8, 2), blk, 0, stream>>>(
            Y, W1T, PART, FF, HD, 512, 4194304);
        reduce_bias_relu_kernel<<<dim3(4096), blk, 0, stream>>>(
            PART, DUAL(ffn_b1, (size_t)l * FF), F1, flags);

        // FFN2: split-K z=8 (Kc=512) -> 512 blocks
        gemm128_splitk<<<dim3(8, 8, 8), blk, 0, stream>>>(
            F1, W2T, PART, HD, FF, 512, 1048576);
        reduce_add_ln<true, 8><<<dim3(BQ * QL), blk, 0, stream>>>(
            PART, DUAL(ffn_b2, (size_t)l * HD), Y,
            DUAL(ln2_g, (size_t)l * HD), DUAL(ln2_b, (size_t)l * HD), X, flags);
    }
    #undef DUAL

    out_write_kernel<<<dim3((BQ * QL * HD) / 256), blk, 0, stream>>>(
        X, d_out, BQ * QL * HD, flags);
}

// Round 16
// 1098.344 us; speedup vs baseline: 1.0059x; 1.0059x over previous
//
#include <hip/hip_runtime.h>
#include <hip/hip_bf16.h>

// Transformer-XL forward, MI355X gfx950.
// Round 17 (resubmit; round-15 bench was a GPU-broker timeout, kernel never
// ran): flash v6 -- collapse the serialized HBM chain with registers.
// Round-14 evidence: wave-fence swap was neutral; 40K cycles/iter ~= 10
// serialized HBM round-trips, and VGPR_Count=64 shows the compiler had no
// registers to hoist loads. Round-2's "preload everything" was right but
// spilled at the 128-VGPR cap of launch_bounds(256,4). v6: issue ALL of an
// iteration's loads (K, R+PR, V, CK, mask) before any consumer, under
// launch_bounds(256,2) (cap 256; est live set ~210). Wave fences + v4 math
// retained. Spill tripwire: WRITE_SIZE must stay ~4MB. Rest unchanged.

#define BQ 2
#define QL 512
#define ML 512
#define CL 1024    // QLEN + MLEN
#define RL 1536    // CLEN + QLEN
#define HD 1024
#define NH 16
#define DH 64
#define FF 4096
#define NLAYER 4

typedef const float* FP;
typedef const __hip_bfloat16* BP;
typedef unsigned short u16;
typedef unsigned long long u64;
typedef __attribute__((ext_vector_type(8))) __bf16 bf16x8;
typedef __attribute__((ext_vector_type(8))) unsigned short u16x8;
typedef __attribute__((ext_vector_type(4))) float f32x4;

static __device__ __forceinline__ float b2f(__hip_bfloat16 x) { return __bfloat162float(x); }
static __device__ __forceinline__ u16 f2u(float f) {
    union { __hip_bfloat16 h; u16 u; } c; c.h = __float2bfloat16(f); return c.u;
}
static __device__ __forceinline__ float u2f(u16 u) {
    union { float f; unsigned int i; } c; c.i = ((unsigned int)u) << 16; return c.f;
}

// wave-local LDS write->read fence: DS ops from one wave are in-order in HW;
// this only pins the compiler's program order (emits no instructions).
static __device__ __forceinline__ void wave_lds_fence() {
    __builtin_amdgcn_wave_barrier();
}

// async 16B global->LDS (gfx950). Per-lane global addr; LDS dest must equal
// wave-uniform base + lane*16B in the exact lane order.
static __device__ __forceinline__ void gll16(const u16* g, u16* l) {
    __builtin_amdgcn_global_load_lds(
        (__attribute__((address_space(1))) void*)(u16*)g,
        (__attribute__((address_space(3))) void*)l, 16, 0, 0);
}

// flags[0] = 1 if float inputs are fp32, 0 if bf16
// flags[1] = 1 if segment_matrix is int32, 0 if int8
__global__ void sniff_kernel(const unsigned int* __restrict__ ln1_gamma,
                             const unsigned char* __restrict__ seg,
                             int* __restrict__ flags) {
    if (threadIdx.x == 0) {
        flags[0] = (ln1_gamma[0] == 0x3F800000u) ? 1 : 0;
        int int32ok = 1;
        for (int i = 0; i < 256; ++i)
            if ((i & 3) != 0 && seg[i] != 0) { int32ok = 0; break; }
        flags[1] = int32ok;
    }
}

__global__ void canon_kernel(FP inf, BP inb, u16* __restrict__ out,
                             int n, const int* __restrict__ flags) {
    int i = blockIdx.x * 256 + threadIdx.x;
    if (i >= n) return;
    out[i] = flags[0] ? f2u(inf[i]) : ((const u16*)inb)[i];
}

__global__ void out_write_kernel(const u16* __restrict__ in, void* __restrict__ out,
                                 int n, const int* __restrict__ flags) {
    int i = blockIdx.x * 256 + threadIdx.x;
    if (i >= n) return;
    if (flags[0]) ((float*)out)[i] = u2f(in[i]);
    else          ((u16*)out)[i] = in[i];
}

// maskT[b][j][i] = bf16(mask[b][i][j] * -1e30) with LSB = segment bit.
__global__ __launch_bounds__(256) void segmask_packT_kernel(
    const void* __restrict__ seg, FP maskf, BP maskb,
    u16* __restrict__ maskT, const int* __restrict__ flags) {
    __shared__ u16 t[32][33];
    const int tid = threadIdx.x;
    const int j0 = blockIdx.x * 32, i0 = blockIdx.y * 32, b = blockIdx.z;
    const int tc = tid & 31, tr = tid >> 5;
    const int f32 = flags[0], s32 = flags[1];
    #pragma unroll
    for (int p = 0; p < 4; ++p) {
        int i = i0 + p * 8 + tr;
        size_t gi = ((size_t)(b * QL + i)) * CL + j0 + tc;
        int sv = s32 ? ((const int*)seg)[gi] : (int)((const signed char*)seg)[gi];
        float mk = f32 ? maskf[gi] : b2f(maskb[gi]);
        t[p * 8 + tr][tc] = (u16)((f2u(mk * -1e30f) & 0xFFFEu) | (sv ? 1u : 0u));
    }
    __syncthreads();
    #pragma unroll
    for (int p = 0; p < 4; ++p) {
        int j = j0 + p * 8 + tr;
        maskT[((size_t)(b * CL + j)) * QL + i0 + tc] = t[tc][p * 8 + tr];
    }
}

// in: R x Cc (dual float), out: Cc x R bf16 (k-contiguous B^T)
__global__ __launch_bounds__(256) void transpose_kernel(
    FP inf, BP inb, u16* __restrict__ out, int R, int Cc,
    const int* __restrict__ flags) {
    __shared__ float t[32][33];
    const int tid = threadIdx.x;
    const int c0 = blockIdx.x * 32, r0 = blockIdx.y * 32;
    const int tc = tid & 31, tr = tid >> 5;
    const int f32 = flags[0];
    #pragma unroll
    for (int p = 0; p < 4; ++p) {
        int r = r0 + p * 8 + tr;
        size_t gi = (size_t)r * Cc + c0 + tc;
        t[p * 8 + tr][tc] = f32 ? inf[gi] : b2f(inb[gi]);
    }
    __syncthreads();
    #pragma unroll
    for (int p = 0; p < 4; ++p) {
        int c = c0 + p * 8 + tr;
        out[(size_t)c * R + r0 + tc] = f2u(t[tc][p * 8 + tr]);
    }
}

// batched 1024x1024 transpose of w_q/w_k/w_v/w_r -> W4 segments (z picks).
__global__ __launch_bounds__(256) void transpose4_kernel(
    FP aqf, BP aqb, FP akf, BP akb, FP avf, BP avb, FP arf, BP arb,
    u16* __restrict__ W4, const int* __restrict__ flags) {
    __shared__ float t[32][33];
    const int tid = threadIdx.x;
    const int c0 = blockIdx.x * 32, r0 = blockIdx.y * 32, z = blockIdx.z;
    const int tc = tid & 31, tr = tid >> 5;
    const int f32 = flags[0];
    FP inf; BP inb;
    if (z == 0)      { inf = aqf; inb = aqb; }
    else if (z == 1) { inf = akf; inb = akb; }
    else if (z == 2) { inf = avf; inb = avb; }
    else             { inf = arf; inb = arb; }
    u16* out = W4 + (size_t)z * (HD * HD);
    #pragma unroll
    for (int p = 0; p < 4; ++p) {
        int r = r0 + p * 8 + tr;
        size_t gi = (size_t)r * HD + c0 + tc;
        t[p * 8 + tr][tc] = f32 ? inf[gi] : b2f(inb[gi]);
    }
    __syncthreads();
    #pragma unroll
    for (int p = 0; p < 4; ++p) {
        int c = c0 + p * 8 + tr;
        out[(size_t)c * HD + r0 + tc] = f2u(t[tc][p * 8 + tr]);
    }
}

// ---------------- 128x128 GEMM core, BK=32, async LDS staging ----------------
__device__ __forceinline__ void gemm128_core(
    const u16* __restrict__ A, int lda, const u16* __restrict__ Bt, int ldb,
    int K, int tid, u16* sA, u16* sB, f32x4 (&acc)[4][4])
{
    const int lane = tid & 63, w = tid >> 6;
    const int wm = (w & 1) * 64, wn = (w >> 1) * 64;
    const int lr = lane & 15, quad = lane >> 4;
    const int srow = lane >> 2;           // 16 rows per instr, 4 lanes/row
    const int sch = (lane & 3) * 8;       // 8 u16 = 16B per lane

    for (int k0 = 0; k0 < K; k0 += 32) {
        #pragma unroll
        for (int j = 0; j < 2; ++j) {     // wave w stages rows w*32+j*16 .. +15
            int rb = w * 32 + j * 16;
            gll16(&A[(size_t)(rb + srow) * lda + k0 + sch], &sA[rb * 32 + lane * 8]);
            gll16(&Bt[(size_t)(rb + srow) * ldb + k0 + sch], &sB[rb * 32 + lane * 8]);
        }
        __syncthreads();                  // drains vmcnt, then barrier
        bf16x8 af[4], bf[4];
        #pragma unroll
        for (int mi = 0; mi < 4; ++mi)
            af[mi] = *(const bf16x8*)&sA[(wm + mi * 16 + lr) * 32 + quad * 8];
        #pragma unroll
        for (int ni = 0; ni < 4; ++ni)
            bf[ni] = *(const bf16x8*)&sB[(wn + ni * 16 + lr) * 32 + quad * 8];
        #pragma unroll
        for (int mi = 0; mi < 4; ++mi)
            #pragma unroll
            for (int ni = 0; ni < 4; ++ni)
                acc[mi][ni] = __builtin_amdgcn_mfma_f32_16x16x32_bf16(
                    af[mi], bf[ni], acc[mi][ni], 0, 0, 0);
        __syncthreads();
    }
}

#define ACC_INIT(acc) \
    _Pragma("unroll") for (int mi = 0; mi < 4; ++mi) \
        _Pragma("unroll") for (int ni = 0; ni < 4; ++ni) \
            acc[mi][ni] = (f32x4){0.f, 0.f, 0.f, 0.f};

// ---------------- merged q/k/v/r projection GEMM (128-tile) ----------------
// K/V segments read context rows directly: ctx row = b*CL + r; r<ML from
// memsB[layer][b], else from X[b]. V segment writes VT[bn][d][j] directly.
__global__ __launch_bounds__(256) void proj4_gemm(
    const u16* __restrict__ X, const u16* __restrict__ memsL,
    const u16* __restrict__ PE, const u16* __restrict__ W4,
    u16* __restrict__ Qb, u16* __restrict__ Kb,
    u16* __restrict__ VT, u16* __restrict__ Rb)
{
    __shared__ __align__(16) u16 sA[128 * 32];
    __shared__ __align__(16) u16 sB[128 * 32];
    const int tid = threadIdx.x;
    const int by = blockIdx.y;
    const u16* Abase; u16* Cbase = nullptr; int seg, mb;
    if (by < 8)       { seg = 0; mb = by;      Abase = X + (size_t)mb * 128 * HD; Cbase = Qb; }
    else if (by < 24) { seg = 1; mb = by - 8;  Cbase = Kb; Abase = nullptr; }
    else if (by < 40) { seg = 2; mb = by - 24; Abase = nullptr; }
    else              { seg = 3; mb = by - 40; Abase = PE + (size_t)mb * 128 * HD; Cbase = Rb; }
    if (seg == 1 || seg == 2) {
        int b = mb >> 3, r0 = (mb & 7) * 128;
        Abase = (r0 < ML) ? memsL + ((size_t)(b * ML + r0)) * HD
                          : X + ((size_t)(b * QL + (r0 - ML))) * HD;
    }
    const int m0 = mb * 128, n0 = blockIdx.x * 128;

    f32x4 acc[4][4];
    ACC_INIT(acc)
    gemm128_core(Abase, HD, W4 + (size_t)seg * HD * HD + (size_t)n0 * HD, HD, HD,
                 tid, sA, sB, acc);

    const int lane = tid & 63, w = tid >> 6;
    const int wm = (w & 1) * 64, wn = (w >> 1) * 64;
    const int lr = lane & 15, quad = lane >> 4;
    if (seg != 2) {
        #pragma unroll
        for (int ni = 0; ni < 4; ++ni) {
            int col = n0 + wn + ni * 16 + lr;
            #pragma unroll
            for (int mi = 0; mi < 4; ++mi) {
                int row = m0 + wm + mi * 16 + quad * 4;
                #pragma unroll
                for (int r = 0; r < 4; ++r)
                    Cbase[(size_t)(row + r) * HD + col] = f2u(acc[mi][ni][r]);
            }
        }
    } else {
        // V: write VT[(b*NH+n)][d][j], j contiguous (4 rows -> ushort4)
        #pragma unroll
        for (int ni = 0; ni < 4; ++ni) {
            int col = n0 + wn + ni * 16 + lr;
            int nh = col >> 6, d = col & 63;
            #pragma unroll
            for (int mi = 0; mi < 4; ++mi) {
                int row = m0 + wm + mi * 16 + quad * 4;
                int b = row >> 10, j = row & 1023;
                ushort4 o;
                #pragma unroll
                for (int r = 0; r < 4; ++r) (&o.x)[r] = f2u(acc[mi][ni][r]);
                *(ushort4*)&VT[(((size_t)(b * NH + nh) * DH + d) * CL + j)] = o;
            }
        }
    }
}

// ---------------- split-K 128-tile GEMM: fp32 partials ----------------
__global__ __launch_bounds__(256) void gemm128_splitk(
    const u16* __restrict__ A, const u16* __restrict__ Bt,
    float* __restrict__ part, int N, int Kfull, int Kc, size_t zstride)
{
    __shared__ __align__(16) u16 sA[128 * 32];
    __shared__ __align__(16) u16 sB[128 * 32];
    const int tid = threadIdx.x;
    const int n0 = blockIdx.x * 128, m0 = blockIdx.y * 128, z = blockIdx.z;
    f32x4 acc[4][4];
    ACC_INIT(acc)
    gemm128_core(A + (size_t)m0 * Kfull + z * Kc, Kfull,
                 Bt + (size_t)n0 * Kfull + z * Kc, Kfull, Kc,
                 tid, sA, sB, acc);

    float* P = part + (size_t)z * zstride;
    const int lane = tid & 63, w = tid >> 6;
    const int wm = (w & 1) * 64, wn = (w >> 1) * 64;
    const int lr = lane & 15, quad = lane >> 4;
    #pragma unroll
    for (int ni = 0; ni < 4; ++ni) {
        int col = n0 + wn + ni * 16 + lr;
        #pragma unroll
        for (int mi = 0; mi < 4; ++mi) {
            int row = m0 + wm + mi * 16 + quad * 4;
            #pragma unroll
            for (int r = 0; r < 4; ++r)
                P[(size_t)(row + r) * N + col] = acc[mi][ni][r];
        }
    }
}

// ---------------- reduce(NPART partials) [+bias] + residual -> LayerNorm ----
template <bool HASBIAS, int NPART>
__global__ __launch_bounds__(256) void reduce_add_ln(
    const float* __restrict__ part, FP biasf, BP biasb,
    const u16* __restrict__ resid, FP gf, BP gb, FP bef, BP beb,
    u16* __restrict__ O, const int* __restrict__ flags)
{
    const int row = blockIdx.x;               // B*QL rows of HD
    const int tid = threadIdx.x;
    const int wid = tid >> 6, lane = tid & 63;
    __shared__ float r1[4], r2[4];
    const int f32 = flags[0];
    float v[4];
    #pragma unroll
    for (int c = 0; c < 4; ++c) {
        int h = c * 256 + tid;
        size_t idx = (size_t)row * HD + h;
        float s = 0.f;
        #pragma unroll
        for (int k = 0; k < NPART; ++k)
            s += part[idx + (size_t)k * 1048576];
        if (HASBIAS) s += f32 ? biasf[h] : b2f(biasb[h]);
        v[c] = s + u2f(resid[idx]);
    }
    float s = v[0] + v[1] + v[2] + v[3];
    #pragma unroll
    for (int o = 32; o > 0; o >>= 1) s += __shfl_xor(s, o);
    if (lane == 0) r1[wid] = s;
    __syncthreads();
    float mu = (r1[0] + r1[1] + r1[2] + r1[3]) * (1.0f / HD);
    float q = 0.f;
    #pragma unroll
    for (int c = 0; c < 4; ++c) { float d = v[c] - mu; q += d * d; }
    #pragma unroll
    for (int o = 32; o > 0; o >>= 1) q += __shfl_xor(q, o);
    if (lane == 0) r2[wid] = q;
    __syncthreads();
    float var = (r2[0] + r2[1] + r2[2] + r2[3]) * (1.0f / HD);
    float inv = rsqrtf(var + 1e-12f);
    #pragma unroll
    for (int c = 0; c < 4; ++c) {
        int h = c * 256 + tid;
        float g = f32 ? gf[h] : b2f(gb[h]);
        float be = f32 ? bef[h] : b2f(beb[h]);
        O[(size_t)row * HD + h] = f2u((v[c] - mu) * inv * g + be);
    }
}

// ---------------- reduce(2 partials) + bias + relu -> bf16 (FFN1) ----------
__global__ __launch_bounds__(256) void reduce_bias_relu_kernel(
    const float* __restrict__ part, FP b1f, BP b1b,
    u16* __restrict__ Out, const int* __restrict__ flags)
{
    const int g = blockIdx.x * 256 + threadIdx.x;       // float4 index
    const float4 p0 = ((const float4*)part)[g];
    const float4 p1 = ((const float4*)(part + 4194304))[g];
    const int col = (g * 4) & (FF - 1);
    const int f32 = flags[0];
    ushort4 o;
    #pragma unroll
    for (int j = 0; j < 4; ++j) {
        float bv = f32 ? b1f[col + j] : b2f(b1b[col + j]);
        float v = (&p0.x)[j] + (&p1.x)[j] + bv;
        (&o.x)[j] = f2u(fmaxf(v, 0.0f));
    }
    ((ushort4*)Out)[g] = o;
}

// ---------------- ef2: (q + segment_bias) . segment_encoding[l] ----------------
__global__ void ef2_kernel(const u16* __restrict__ Qb, FP sbf, BP sbb,
                           FP sef, BP seb, float* __restrict__ EF,
                           const int* __restrict__ flags) {
    int t = blockIdx.x * 256 + threadIdx.x;
    if (t >= BQ * NH * QL) return;
    int i = t % QL;
    int n = (t / QL) % NH;
    int b = t / (QL * NH);
    float e0 = 0.f, e1 = 0.f;
    const int f32 = flags[0];
    const u16* qrow = &Qb[((size_t)(b * QL + i) * NH + n) * DH];
    for (int d0 = 0; d0 < DH; d0 += 8) {
        u16x8 qv = *(const u16x8*)&qrow[d0];
        #pragma unroll
        for (int j = 0; j < 8; ++j) {
            int d = d0 + j;
            float sbv = f32 ? sbf[n * DH + d] : b2f(sbb[n * DH + d]);
            float s0 = f32 ? sef[(0 * NH + n) * DH + d] : b2f(seb[(0 * NH + n) * DH + d]);
            float s1 = f32 ? sef[(1 * NH + n) * DH + d] : b2f(seb[(1 * NH + n) * DH + d]);
            float qv_f = u2f(qv[j]) + sbv;
            e0 += qv_f * s0;
            e1 += qv_f * s1;
        }
    }
    EF[(size_t)t * 2 + 0] = e0;
    EF[(size_t)t * 2 + 1] = e1;
}

// ---------------- CK[bn][j] = cb_n . k_j ; PR[bn][rr] = pb_n . r_rr ----------------
__global__ void ckpr_kernel(const u16* __restrict__ Kb, const u16* __restrict__ Rb,
                            FP cbf, BP cbb, FP pbf, BP pbb,
                            float* __restrict__ CK, float* __restrict__ PR,
                            const int* __restrict__ flags) {
    int t = blockIdx.x * 256 + threadIdx.x;
    const int f32 = flags[0];
    if (t < 32 * CL) {
        int bn = t >> 10, j = t & (CL - 1);
        int b = bn >> 4, n = bn & 15;
        float s = 0.f;
        const u16* krow = &Kb[((size_t)(b * CL + j) * NH + n) * DH];
        for (int d0 = 0; d0 < DH; d0 += 8) {
            u16x8 kv = *(const u16x8*)&krow[d0];
            #pragma unroll
            for (int jj = 0; jj < 8; ++jj) {
                int d = d0 + jj;
                float c = f32 ? cbf[n * DH + d] : b2f(cbb[n * DH + d]);
                s += c * u2f(kv[jj]);
            }
        }
        CK[t] = s;
    } else {
        int t2 = t - 32 * CL;
        if (t2 >= 32 * RL) return;
        int bn = t2 / RL, rr = t2 % RL;
        int b = bn >> 4, n = bn & 15;
        float s = 0.f;
        const u16* rrow = &Rb[((size_t)(b * RL + rr) * NH + n) * DH];
        for (int d0 = 0; d0 < DH; d0 += 8) {
            u16x8 rv = *(const u16x8*)&rrow[d0];
            #pragma unroll
            for (int jj = 0; jj < 8; ++jj) {
                int d = d0 + jj;
                float c = f32 ? pbf[n * DH + d] : b2f(pbb[n * DH + d]);
                s += c * u2f(rv[jj]);
            }
        }
        PR[(size_t)bn * RL + rr] = s;
    }
}

// ---------------- fused flash attention v6 ----------------
// v5 wave-fence structure + ALL per-iteration global loads issued before any
// consumer (collapses ~10 serialized HBM waits to ~2), enabled by the
// 256-VGPR budget of launch_bounds(256,2). Est live set ~210 VGPR, no spill.
#define FA_SP 72
#define FA_SD 84
__global__ __launch_bounds__(256, 2) void flash_attn_kernel(
    const u16* __restrict__ Qb, const u16* __restrict__ Kb,
    const u16* __restrict__ Rb, const u16* __restrict__ VT,
    const float* __restrict__ CK, const float* __restrict__ PR,
    const float* __restrict__ EF,
    const u16* __restrict__ maskT, u16* __restrict__ AT)
{
    __shared__ __align__(16) u16 sP[4][16 * FA_SP];
    __shared__ __align__(16) float sD[4][16 * FA_SD];   // cmb aliases after loop

    const int tid = threadIdx.x;
    const int w = tid >> 6;
    const int lane = tid & 63;
    const int lr = lane & 15, quad = lane >> 4;

    const int blin = blockIdx.x;
    const int xcd = blin & 7, slot = blin >> 3;
    const int bn = xcd + 8 * (slot >> 5);      // head; all 32 i-tiles same XCD
    const int itile = slot & 31;
    const int b = bn >> 4, n = bn & 15;
    const int i0 = itile * 16;

    u16* myP = sP[w];
    float* myD = sD[w];

    const size_t qoff = ((size_t)(b * QL + i0 + lr) * NH + n) * DH + quad * 8;
    const bf16x8 q0 = *(const bf16x8*)&Qb[qoff];
    const bf16x8 q1 = *(const bf16x8*)&Qb[qoff + 32];

    float ef0[4], ef1[4];
    #pragma unroll
    for (int r = 0; r < 4; ++r) {
        size_t e = ((size_t)bn * QL + i0 + quad * 4 + r) * 2;
        ef0[r] = EF[e]; ef1[r] = EF[e + 1];
    }

    f32x4 accO[4];
    #pragma unroll
    for (int c = 0; c < 4; ++c) accO[c] = (f32x4){0.f, 0.f, 0.f, 0.f};
    float m[4], l[4];
    #pragma unroll
    for (int r = 0; r < 4; ++r) { m[r] = -1e38f; l[r] = 0.f; }

    #pragma unroll 1
    for (int t = 0; t < 4; ++t) {
        const int j0 = w * 64 + t * 256;
        const int base16 = 497 - i0 + j0;     // rr at p=0; p = 15-ilw+jl

        // ---- issue ALL global loads for this tile before any consumer ----
        bf16x8 kf[8];
        const u16* kbase = &Kb[((size_t)(b * CL + j0 + lr) * NH + n) * DH + quad * 8];
        #pragma unroll
        for (int ct = 0; ct < 4; ++ct) {
            const u16* kp = kbase + (size_t)ct * 16 * (NH * DH);
            kf[ct * 2]     = *(const bf16x8*)kp;
            kf[ct * 2 + 1] = *(const bf16x8*)(kp + 32);
        }
        bf16x8 rf[10]; float prv[5];
        #pragma unroll
        for (int f = 0; f < 5; ++f) {
            int rr = base16 + f * 16 + lr;
            rr = rr > RL - 1 ? RL - 1 : rr;   // p>=79 lanes: computed, never read
            const u16* rp = &Rb[((size_t)(b * RL + rr) * NH + n) * DH + quad * 8];
            rf[f * 2]     = *(const bf16x8*)rp;
            rf[f * 2 + 1] = *(const bf16x8*)(rp + 32);
            prv[f] = PR[(size_t)bn * RL + rr];
        }
        bf16x8 vf[8];
        #pragma unroll
        for (int ct = 0; ct < 4; ++ct) {
            const u16* vp = &VT[((size_t)bn * DH + ct * 16 + lr) * CL + j0 + quad * 8];
            vf[ct * 2]     = *(const bf16x8*)vp;
            vf[ct * 2 + 1] = *(const bf16x8*)(vp + 32);
        }
        float ckv[4];
        u64 mq[4];
        #pragma unroll
        for (int ct = 0; ct < 4; ++ct) {
            ckv[ct] = CK[(size_t)bn * CL + j0 + ct * 16 + lr];
            mq[ct] = *(const u64*)&maskT[((size_t)(b * CL + j0 + ct * 16 + lr)) * QL + i0 + quad * 4];
        }

        // ---- QK ----
        f32x4 acc[4];
        #pragma unroll
        for (int c = 0; c < 4; ++c) acc[c] = (f32x4){0.f, 0.f, 0.f, 0.f};
        #pragma unroll
        for (int ct = 0; ct < 4; ++ct) {
            acc[ct] = __builtin_amdgcn_mfma_f32_16x16x32_bf16(q0, kf[ct * 2], acc[ct], 0, 0, 0);
            acc[ct] = __builtin_amdgcn_mfma_f32_16x16x32_bf16(q1, kf[ct * 2 + 1], acc[ct], 0, 0, 0);
        }

        // ---- bd: 10 MFMA -> LDS ----
        #pragma unroll
        for (int f = 0; f < 5; ++f) {
            f32x4 bd = (f32x4){0.f, 0.f, 0.f, 0.f};
            bd = __builtin_amdgcn_mfma_f32_16x16x32_bf16(q0, rf[f * 2], bd, 0, 0, 0);
            bd = __builtin_amdgcn_mfma_f32_16x16x32_bf16(q1, rf[f * 2 + 1], bd, 0, 0, 0);
            #pragma unroll
            for (int r = 0; r < 4; ++r)
                myD[(quad * 4 + r) * FA_SD + f * 16 + lr] = bd[r] + prv[f];
        }
        wave_lds_fence();   // wave-local handoff: bd writes -> score reads

        // ---- scores ----
        #pragma unroll
        for (int ct = 0; ct < 4; ++ct) {
            #pragma unroll
            for (int r = 0; r < 4; ++r) {
                int ilw = quad * 4 + r;
                int p = 15 - ilw + ct * 16 + lr;
                float bdv = myD[ilw * FA_SD + p];
                u16 mv = (u16)(mq[ct] >> (16 * r));
                float efv = (mv & 1) ? ef1[r] : ef0[r];
                float mka = u2f((u16)(mv & 0xFFFEu));
                acc[ct][r] = (acc[ct][r] + bdv + ckv[ct] + efv) * 0.125f + mka;
            }
        }

        // ---- online softmax ----
        float a[4];
        #pragma unroll
        for (int r = 0; r < 4; ++r) {
            float tm = fmaxf(fmaxf(acc[0][r], acc[1][r]), fmaxf(acc[2][r], acc[3][r]));
            tm = fmaxf(tm, __shfl_xor(tm, 1));
            tm = fmaxf(tm, __shfl_xor(tm, 2));
            tm = fmaxf(tm, __shfl_xor(tm, 4));
            tm = fmaxf(tm, __shfl_xor(tm, 8));
            float mn = fmaxf(m[r], tm);
            a[r] = __expf(m[r] - mn);
            m[r] = mn;
        }
        float ts[4] = {0.f, 0.f, 0.f, 0.f};
        #pragma unroll
        for (int ct = 0; ct < 4; ++ct)
            #pragma unroll
            for (int r = 0; r < 4; ++r) {
                float pv = __expf(acc[ct][r] - m[r]);
                ts[r] += pv;
                myP[(quad * 4 + r) * FA_SP + ct * 16 + lr] = f2u(pv);
            }
        #pragma unroll
        for (int r = 0; r < 4; ++r) {
            float s = ts[r];
            s += __shfl_xor(s, 1);
            s += __shfl_xor(s, 2);
            s += __shfl_xor(s, 4);
            s += __shfl_xor(s, 8);
            l[r] = l[r] * a[r] + s;
            #pragma unroll
            for (int c = 0; c < 4; ++c) accO[c][r] *= a[r];
        }
        wave_lds_fence();   // wave-local handoff: P writes -> PV reads

        // ---- PV ----
        const bf16x8 pa0 = *(const bf16x8*)&myP[lr * FA_SP + quad * 8];
        const bf16x8 pa1 = *(const bf16x8*)&myP[lr * FA_SP + 32 + quad * 8];
        #pragma unroll
        for (int ct = 0; ct < 4; ++ct) {
            accO[ct] = __builtin_amdgcn_mfma_f32_16x16x32_bf16(pa0, vf[ct * 2], accO[ct], 0, 0, 0);
            accO[ct] = __builtin_amdgcn_mfma_f32_16x16x32_bf16(pa1, vf[ct * 2 + 1], accO[ct], 0, 0, 0);
        }
    }
    // ---- merge the 4 j-split partials (LDS aliased over sD), write AT ----
    __syncthreads();                         // cross-wave: all done with sD scratch
    float* cmb = &sD[0][0];
    if (w != 0) {
        float* c = &cmb[((w - 1) * 64 + lane) * 25];
        #pragma unroll
        for (int ct = 0; ct < 4; ++ct)
            #pragma unroll
            for (int r = 0; r < 4; ++r) c[ct * 4 + r] = accO[ct][r];
        #pragma unroll
        for (int r = 0; r < 4; ++r) { c[16 + r] = m[r]; c[20 + r] = l[r]; }
    }
    __syncthreads();
    if (w == 0) {
        float M[4], es[4], eo[3][4], lt[4];
        #pragma unroll
        for (int r = 0; r < 4; ++r) M[r] = m[r];
        #pragma unroll
        for (int k = 0; k < 3; ++k) {
            const float* c = &cmb[(k * 64 + lane) * 25];
            #pragma unroll
            for (int r = 0; r < 4; ++r) M[r] = fmaxf(M[r], c[16 + r]);
        }
        #pragma unroll
        for (int r = 0; r < 4; ++r) { es[r] = __expf(m[r] - M[r]); lt[r] = l[r] * es[r]; }
        #pragma unroll
        for (int k = 0; k < 3; ++k) {
            const float* c = &cmb[(k * 64 + lane) * 25];
            #pragma unroll
            for (int r = 0; r < 4; ++r) {
                eo[k][r] = __expf(c[16 + r] - M[r]);
                lt[r] += c[20 + r] * eo[k][r];
            }
        }
        #pragma unroll
        for (int ct = 0; ct < 4; ++ct)
            #pragma unroll
            for (int r = 0; r < 4; ++r) {
                float o = accO[ct][r] * es[r];
                #pragma unroll
                for (int k = 0; k < 3; ++k)
                    o += cmb[(k * 64 + lane) * 25 + ct * 4 + r] * eo[k][r];
                AT[((size_t)(b * QL + i0 + quad * 4 + r) * NH + n) * DH + ct * 16 + lr]
                    = f2u(o / lt[r]);
            }
    }
}

extern "C" void kernel_launch(void* const* d_in, const int* in_sizes, int n_in,
                              void* d_out, int out_size, void* d_ws, size_t ws_size,
                              hipStream_t stream) {
    (void)in_sizes; (void)n_in; (void)out_size; (void)ws_size;
    const void* content_stream = d_in[0];
    const void* content_mask   = d_in[1];
    const void* pos_enc        = d_in[2];
    const void* seg_mat        = d_in[3];
    const void* mems           = d_in[4];
    const void* w_q            = d_in[5];
    const void* w_k            = d_in[6];
    const void* w_v            = d_in[7];
    const void* w_r            = d_in[8];
    const void* w_o            = d_in[9];
    const void* ffn_w1         = d_in[10];
    const void* ffn_b1         = d_in[11];
    const void* ffn_w2         = d_in[12];
    const void* ffn_b2         = d_in[13];
    const void* ln1_g          = d_in[14];
    const void* ln1_b          = d_in[15];
    const void* ln2_g          = d_in[16];
    const void* ln2_b          = d_in[17];
    const void* cb             = d_in[18];
    const void* pb             = d_in[19];
    const void* sb             = d_in[20];
    const void* se             = d_in[21];

    float* SC    = (float*)d_ws;              // F1 0..8MB
    float* PART  = SC + 4194304;              // +16MB..+48MB (8x4MB / 2x16MB)
    float* EF    = SC + 16777216;             // +64MB
    float* CK    = EF + 32768;
    float* PR    = CK + 32768;
    int*   flags = (int*)(PR + 49152);
    u16*   bws   = (u16*)(flags + 16);

    u16* MEMSB = bws;                 // L*B*ML*HD bf16 (8MB)
    u16* X   = MEMSB + 4194304;       u16* Y   = X   + 1048576;
    u16* Qb  = Y   + 1048576;         u16* Kb  = Qb  + 1048576;
    u16* Rb  = Kb  + 2097152;         u16* PE  = Rb  + 3145728;
    u16* AT  = PE  + 3145728;
    u16* W4  = AT  + 1048576;         // WQT|WKT|WVT|WRT contiguous
    u16* WOc = W4  + 4194304;         u16* W1T = WOc + 1048576;
    u16* W2T = W1T + 4194304;
    u16* F1  = (u16*)SC;              // bytes 0..8MB
    u16* VT  = (u16*)(SC + 12582912); // +48MB..+52MB
    u16* maskT = (u16*)(SC + 13631488); // +52MB..+54MB

    const size_t wstride   = (size_t)HD * HD;

    const dim3 blk(256);
    #define DUAL(base, off) ((FP)(base) + (off)), ((BP)(base) + (off))

    sniff_kernel<<<dim3(1), dim3(64), 0, stream>>>(
        (const unsigned int*)ln1_g, (const unsigned char*)seg_mat, flags);

    canon_kernel<<<dim3((BQ * QL * HD) / 256), blk, 0, stream>>>(
        DUAL(content_stream, 0), X, BQ * QL * HD, flags);
    canon_kernel<<<dim3((BQ * RL * HD) / 256), blk, 0, stream>>>(
        DUAL(pos_enc, 0), PE, BQ * RL * HD, flags);
    canon_kernel<<<dim3((NLAYER * BQ * ML * HD) / 256), blk, 0, stream>>>(
        DUAL(mems, 0), MEMSB, NLAYER * BQ * ML * HD, flags);
    segmask_packT_kernel<<<dim3(CL / 32, QL / 32, BQ), blk, 0, stream>>>(
        seg_mat, DUAL(content_mask, 0), maskT, flags);

    for (int l = 0; l < NLAYER; ++l) {
        transpose4_kernel<<<dim3(32, 32, 4), blk, 0, stream>>>(
            DUAL(w_q, (size_t)l * wstride), DUAL(w_k, (size_t)l * wstride),
            DUAL(w_v, (size_t)l * wstride), DUAL(w_r, (size_t)l * wstride),
            W4, flags);
        canon_kernel<<<dim3((HD * HD) / 256), blk, 0, stream>>>(
            DUAL(w_o, (size_t)l * wstride), WOc, HD * HD, flags);
        transpose_kernel<<<dim3(FF / 32, HD / 32), blk, 0, stream>>>(
            DUAL(ffn_w1, (size_t)l * HD * FF), W1T, HD, FF, flags);
        transpose_kernel<<<dim3(HD / 32, FF / 32), blk, 0, stream>>>(
            DUAL(ffn_w2, (size_t)l * FF * HD), W2T, FF, HD, flags);

        proj4_gemm<<<dim3(8, 64), blk, 0, stream>>>(
            X, MEMSB + (size_t)l * BQ * ML * HD, PE, W4, Qb, Kb, VT, Rb);

        ef2_kernel<<<dim3((BQ * NH * QL) / 256), blk, 0, stream>>>(
            Qb, DUAL(sb, 0), DUAL(se, (size_t)l * 2 * NH * DH), EF, flags);
        ckpr_kernel<<<dim3((32 * CL + 32 * RL) / 256), blk, 0, stream>>>(
            Kb, Rb, DUAL(cb, 0), DUAL(pb, 0), CK, PR, flags);

        flash_attn_kernel<<<dim3(1024), blk, 0, stream>>>(
            Qb, Kb, Rb, VT, CK, PR, EF, maskT, AT);

        // o-proj: split-K z=8 (Kc=128) -> 512 blocks
        gemm128_splitk<<<dim3(8, 8, 8), blk, 0, stream>>>(
            AT, WOc, PART, HD, HD, 128, 1048576);
        reduce_add_ln<false, 8><<<dim3(BQ * QL), blk, 0, stream>>>(
            PART, (FP)nullptr, (BP)nullptr, X,
            DUAL(ln1_g, (size_t)l * HD), DUAL(ln1_b, (size_t)l * HD), Y, flags);

        // FFN1: split-K z=2 (Kc=512) -> 512 blocks; reduce+bias+relu pass
        gemm128_splitk<<<dim3(FF / 128, 8, 2), blk, 0, stream>>>(
            Y, W1T, PART, FF, HD, 512, 4194304);
        reduce_bias_relu_kernel<<<dim3(4096), blk, 0, stream>>>(
            PART, DUAL(ffn_b1, (size_t)l * FF), F1, flags);

        // FFN2: split-K z=8 (Kc=512) -> 512 blocks
        gemm128_splitk<<<dim3(8, 8, 8), blk, 0, stream>>>(
            F1, W2T, PART, HD, FF, 512, 1048576);
        reduce_add_ln<true, 8><<<dim3(BQ * QL), blk, 0, stream>>>(
            PART, DUAL(ffn_b2, (size_t)l * HD), Y,
            DUAL(ln2_g, (size_t)l * HD), DUAL(ln2_b, (size_t)l * HD), X, flags);
    }
    #undef DUAL

    out_write_kernel<<<dim3((BQ * QL * HD) / 256), blk, 0, stream>>>(
        X, d_out, BQ * QL * HD, flags);
}